// Round 1
// baseline (457.366 us; speedup 1.0000x reference)
//
#include <hip/hip_runtime.h>
#include <hip/hip_bf16.h>
#include <stdint.h>

// Problem constants
// B=16, L=512, DIM=2048, H=32, HKV=8, DH=64, REP=4, S=8192
// q = rope(x@wq.T), k = rope(x@wk.T), v = x@wv.T
// attn per (b, h): softmax(q k^T / 8) v   (non-causal, full 512x512)
// out = attn @ wo.T
//
// Pipeline (all bf16 MFMA, fp32 accum):
//   cvt x->xb, wq/wk/wv->wqkvb (stacked N=3072), wo->wob
//   gemm_bt: xqkv(bf16, 8192x3072) = xb @ wqkvb^T
//   rope_q/rope_k/conv_vt: layout + rope into q (B,H,L,DH), k (B,HKV,L,DH), vt (B,HKV,DH,L)
//   attn_kernel: flash attention -> attn bf16 (S, H*DH)  [reuses xb region]
//   gemm_bt: d_out(f32) = attn @ wob^T

using bf16 = __hip_bfloat16;
typedef __bf16 bf16x8 __attribute__((ext_vector_type(8)));
typedef float f32x4 __attribute__((ext_vector_type(4)));
typedef float f32x4v __attribute__((ext_vector_type(4)));

__device__ __forceinline__ void gload_lds16(const void* g, void* l) {
  __builtin_amdgcn_global_load_lds((const __attribute__((address_space(1))) void*)g,
                                   (__attribute__((address_space(3))) void*)l, 16, 0, 0);
}

// ---------------- fp32 -> bf16 convert (vectorized) ----------------
__global__ __launch_bounds__(256) void cvt_kernel(const float* __restrict__ in,
                                                  bf16* __restrict__ out, int n4) {
  int i = blockIdx.x * 256 + threadIdx.x;
  if (i >= n4) return;
  f32x4v v = reinterpret_cast<const f32x4v*>(in)[i];
  union { bf16 b[4]; ushort4 u; } cv;
  cv.b[0] = __float2bfloat16(v.x);
  cv.b[1] = __float2bfloat16(v.y);
  cv.b[2] = __float2bfloat16(v.z);
  cv.b[3] = __float2bfloat16(v.w);
  reinterpret_cast<ushort4*>(out)[i] = cv.u;
}

// ---------------- NT GEMM: C[m][n] = sum_k A[m][k] * B[n][k] ----------------
// m97 structure: 128x128 tile, BK=64, 4 waves (2x2), global_load_lds width 16.
template <bool OUT_BF16>
__global__ __launch_bounds__(256) void gemm_bt_kernel(const bf16* __restrict__ A,
                                                      const bf16* __restrict__ Bm,
                                                      void* __restrict__ C,
                                                      int M, int N, int K) {
  __shared__ bf16 As[128 * 64];
  __shared__ bf16 Bs[128 * 64];
  const int t = threadIdx.x;
  const int wid = t >> 6, lane = t & 63;
  const int lrow = lane & 15, lk = lane >> 4;
  const int m0 = blockIdx.x * 128, n0 = blockIdx.y * 128;
  const int wm = (wid >> 1) * 64, wn = (wid & 1) * 64;

  const bf16* Ap = A + (size_t)m0 * K;
  const bf16* Bp = Bm + (size_t)n0 * K;

  f32x4 acc[4][4] = {};

  for (int k0 = 0; k0 < K; k0 += 64) {
    // stage 128x64 A and B tiles: 1024 16B chunks each, 4 per thread
#pragma unroll
    for (int i = 0; i < 4; ++i) {
      int c = i * 256 + t;
      int row = c >> 3, c8 = c & 7;
      gload_lds16(Ap + (size_t)row * K + k0 + c8 * 8, As + c * 8);
      gload_lds16(Bp + (size_t)row * K + k0 + c8 * 8, Bs + c * 8);
    }
    __syncthreads();
#pragma unroll
    for (int kk = 0; kk < 2; ++kk) {
      bf16x8 af[4], bfr[4];
#pragma unroll
      for (int i = 0; i < 4; ++i) {
        int ar = wm + i * 16 + lrow;
        af[i] = *reinterpret_cast<const bf16x8*>(&As[ar * 64 + kk * 32 + lk * 8]);
        int br = wn + i * 16 + lrow;
        bfr[i] = *reinterpret_cast<const bf16x8*>(&Bs[br * 64 + kk * 32 + lk * 8]);
      }
#pragma unroll
      for (int i = 0; i < 4; ++i)
#pragma unroll
        for (int j = 0; j < 4; ++j)
          acc[i][j] = __builtin_amdgcn_mfma_f32_16x16x32_bf16(af[i], bfr[j], acc[i][j], 0, 0, 0);
    }
    __syncthreads();
  }

  // epilogue: C/D layout col=lane&15, row=(lane>>4)*4+reg  [m89 verified]
  if constexpr (OUT_BF16) {
    bf16* Cp = (bf16*)C;
#pragma unroll
    for (int i = 0; i < 4; ++i)
#pragma unroll
      for (int j = 0; j < 4; ++j)
#pragma unroll
        for (int r = 0; r < 4; ++r) {
          int row = m0 + wm + i * 16 + lk * 4 + r;
          int col = n0 + wn + j * 16 + lrow;
          Cp[(size_t)row * N + col] = __float2bfloat16(acc[i][j][r]);
        }
  } else {
    float* Cp = (float*)C;
#pragma unroll
    for (int i = 0; i < 4; ++i)
#pragma unroll
      for (int j = 0; j < 4; ++j)
#pragma unroll
        for (int r = 0; r < 4; ++r) {
          int row = m0 + wm + i * 16 + lk * 4 + r;
          int col = n0 + wn + j * 16 + lrow;
          Cp[(size_t)row * N + col] = acc[i][j][r];
        }
  }
}

// ---------------- RoPE + layout: xqkv (S,3072) -> q/k (B,heads,L,DH) ----------------
template <int HB>  // heads = 1<<HB
__global__ __launch_bounds__(256) void rope_kernel(const bf16* __restrict__ xqkv,
                                                   const float* __restrict__ fc,
                                                   const float* __restrict__ fs,
                                                   bf16* __restrict__ out, int coloff) {
  int i = blockIdx.x * 256 + threadIdx.x;  // (s, head, pair)
  int dp = i & 31;
  int hh = (i >> 5) & ((1 << HB) - 1);
  int s = i >> (5 + HB);
  size_t base = (size_t)s * 3072 + coloff + hh * 64 + 2 * dp;
  float a = __bfloat162float(xqkv[base]);
  float b = __bfloat162float(xqkv[base + 1]);
  float c = fc[s * 32 + dp], sn = fs[s * 32 + dp];
  int bb = s >> 9, l = s & 511;
  size_t o = ((((size_t)bb << HB) + hh) * 512 + l) * 64 + 2 * dp;
  out[o] = __float2bfloat16(a * c - b * sn);
  out[o + 1] = __float2bfloat16(a * sn + b * c);
}

// ---------------- V transpose: xqkv cols [2560,3072) -> vt (B,HKV,DH,L) ----------------
__global__ __launch_bounds__(256) void convvt_kernel(const bf16* __restrict__ xqkv,
                                                     bf16* __restrict__ vt) {
  int i = blockIdx.x * 256 + threadIdx.x;  // (s, g, d)
  int d = i & 63;
  int g = (i >> 6) & 7;
  int s = i >> 9;
  int bb = s >> 9, l = s & 511;
  vt[((size_t)(bb * 8 + g) * 64 + d) * 512 + l] = xqkv[(size_t)s * 3072 + 2560 + g * 64 + d];
}

// ---------------- Flash attention ----------------
// grid: B*H*(L/64) blocks of 256 threads (4 waves, 16 q-rows each), KB=64.
// K and V^T tiles staged in XOR-swizzled LDS (byte ^= (row&7)<<4).
__global__ __launch_bounds__(256) void attn_kernel(const bf16* __restrict__ q,
                                                   const bf16* __restrict__ kg,
                                                   const bf16* __restrict__ vt,
                                                   bf16* __restrict__ attn) {
  __shared__ bf16 Ks[64 * 64];
  __shared__ bf16 Vs[64 * 64];
  __shared__ bf16 Ps[4 * 16 * 64];
  const int t = threadIdx.x;
  const int wid = t >> 6, lane = t & 63;
  const int lrow = lane & 15, lk = lane >> 4;
  const int bid = blockIdx.x;
  const int qt = bid & 7, h = (bid >> 3) & 31, b = bid >> 8;
  const int g = h >> 2;  // REP=4

  const bf16* qp = q + ((size_t)(b * 32 + h) * 512 + qt * 64 + wid * 16) * 64;
  const bf16* kp = kg + ((size_t)(b * 8 + g) * 512) * 64;
  const bf16* vp = vt + ((size_t)(b * 8 + g) * 64) * 512;

  // Q fragments for this wave's 16 rows (held all kernel)
  bf16x8 qf[2];
#pragma unroll
  for (int c = 0; c < 2; ++c)
    qf[c] = *reinterpret_cast<const bf16x8*>(qp + lrow * 64 + c * 32 + lk * 8);

  float m_r[4] = {-1e30f, -1e30f, -1e30f, -1e30f};
  float l_r[4] = {0.f, 0.f, 0.f, 0.f};
  f32x4 oacc[4] = {};

  char* Kb = (char*)Ks;
  char* Vb = (char*)Vs;
  char* Pw = (char*)Ps + wid * 2048;

  for (int kt = 0; kt < 8; ++kt) {
    __syncthreads();
    // stage K tile (64 rows x 64 d) and V^T tile (64 d x 64 m), swizzled
#pragma unroll
    for (int i = 0; i < 2; ++i) {
      int c = i * 256 + t;
      int row = c >> 3, c8 = c & 7;
      bf16x8 kv = *reinterpret_cast<const bf16x8*>(kp + (size_t)(kt * 64 + row) * 64 + c8 * 8);
      bf16x8 vv = *reinterpret_cast<const bf16x8*>(vp + (size_t)row * 512 + kt * 64 + c8 * 8);
      int wb = (row * 128 + c8 * 16) ^ ((row & 7) << 4);
      *reinterpret_cast<bf16x8*>(Kb + wb) = kv;
      *reinterpret_cast<bf16x8*>(Vb + wb) = vv;
    }
    __syncthreads();

    // S = Q K^T  (16 x 64 per wave)
    f32x4 sacc[4] = {};
#pragma unroll
    for (int c = 0; c < 2; ++c) {
      bf16x8 kf[4];
#pragma unroll
      for (int n = 0; n < 4; ++n) {
        int mr = n * 16 + lrow;
        int rb = (mr * 128 + c * 64 + lk * 16) ^ ((mr & 7) << 4);
        kf[n] = *reinterpret_cast<const bf16x8*>(Kb + rb);
      }
#pragma unroll
      for (int n = 0; n < 4; ++n)
        sacc[n] = __builtin_amdgcn_mfma_f32_16x16x32_bf16(qf[c], kf[n], sacc[n], 0, 0, 0);
    }

#pragma unroll
    for (int n = 0; n < 4; ++n)
#pragma unroll
      for (int j = 0; j < 4; ++j) sacc[n][j] *= 0.125f;

    // online softmax: lane holds rows lk*4+j, col lrow+16n; reduce across 16 lanes
    float cfac[4];
#pragma unroll
    for (int j = 0; j < 4; ++j) {
      float v = fmaxf(fmaxf(sacc[0][j], sacc[1][j]), fmaxf(sacc[2][j], sacc[3][j]));
      v = fmaxf(v, __shfl_xor(v, 1));
      v = fmaxf(v, __shfl_xor(v, 2));
      v = fmaxf(v, __shfl_xor(v, 4));
      v = fmaxf(v, __shfl_xor(v, 8));
      float mn = fmaxf(m_r[j], v);
      cfac[j] = __expf(m_r[j] - mn);
      m_r[j] = mn;
    }
    float rsum[4] = {0.f, 0.f, 0.f, 0.f};
#pragma unroll
    for (int n = 0; n < 4; ++n)
#pragma unroll
      for (int j = 0; j < 4; ++j) {
        float p = __expf(sacc[n][j] - m_r[j]);
        sacc[n][j] = p;
        rsum[j] += p;
      }
#pragma unroll
    for (int j = 0; j < 4; ++j) {
      float v = rsum[j];
      v += __shfl_xor(v, 1);
      v += __shfl_xor(v, 2);
      v += __shfl_xor(v, 4);
      v += __shfl_xor(v, 8);
      l_r[j] = l_r[j] * cfac[j] + v;
#pragma unroll
      for (int n = 0; n < 4; ++n) oacc[n][j] *= cfac[j];
    }

    // P -> per-wave LDS (swizzled), then PV mfma
#pragma unroll
    for (int n = 0; n < 4; ++n)
#pragma unroll
      for (int j = 0; j < 4; ++j) {
        int row = lk * 4 + j, col = n * 16 + lrow;
        int wb = (row * 128 + col * 2) ^ ((row & 7) << 4);
        *reinterpret_cast<bf16*>(Pw + wb) = __float2bfloat16(sacc[n][j]);
      }
#pragma unroll
    for (int ms = 0; ms < 2; ++ms) {
      int ab = (lrow * 128 + ms * 64 + lk * 16) ^ ((lrow & 7) << 4);
      bf16x8 pa = *reinterpret_cast<const bf16x8*>(Pw + ab);
#pragma unroll
      for (int n = 0; n < 4; ++n) {
        int dr = n * 16 + lrow;
        int vb2 = (dr * 128 + ms * 64 + lk * 16) ^ ((dr & 7) << 4);
        bf16x8 vf = *reinterpret_cast<const bf16x8*>(Vb + vb2);
        oacc[n] = __builtin_amdgcn_mfma_f32_16x16x32_bf16(pa, vf, oacc[n], 0, 0, 0);
      }
    }
  }

  // epilogue: attn[s][h*64+d] = o / l
  const int qrow = qt * 64 + wid * 16;
  float invl[4];
#pragma unroll
  for (int j = 0; j < 4; ++j) invl[j] = 1.f / l_r[j];
#pragma unroll
  for (int n = 0; n < 4; ++n)
#pragma unroll
    for (int j = 0; j < 4; ++j) {
      size_t row = (size_t)b * 512 + qrow + lk * 4 + j;
      attn[row * 2048 + h * 64 + n * 16 + lrow] = __float2bfloat16(oacc[n][j] * invl[j]);
    }
}

extern "C" void kernel_launch(void* const* d_in, const int* in_sizes, int n_in,
                              void* d_out, int out_size, void* d_ws, size_t ws_size,
                              hipStream_t stream) {
  const float* x = (const float*)d_in[0];
  const float* fc = (const float*)d_in[1];
  const float* fs = (const float*)d_in[2];
  const float* wq = (const float*)d_in[3];
  const float* wk = (const float*)d_in[4];
  const float* wv = (const float*)d_in[5];
  const float* wo = (const float*)d_in[6];

  char* ws = (char*)d_ws;
  // workspace layout (bytes); total 155,189,248
  bf16* xb = (bf16*)(ws + 0);                 // 8192x2048 bf16 (x); reused for attn out
  bf16* wqkvb = (bf16*)(ws + 33554432);       // 3072x2048 bf16 (wq|wk|wv stacked)
  bf16* wob = (bf16*)(ws + 46137344);         // 2048x2048 bf16
  bf16* xqkv = (bf16*)(ws + 54525952);        // 8192x3072 bf16
  bf16* qb = (bf16*)(ws + 104857600);         // (B,32,512,64) bf16
  bf16* kb = (bf16*)(ws + 138412032);         // (B,8,512,64) bf16
  bf16* vtb = (bf16*)(ws + 146800640);        // (B,8,64,512) bf16
  bf16* attn = xb;

  cvt_kernel<<<16384, 256, 0, stream>>>(x, xb, 4194304);
  cvt_kernel<<<4096, 256, 0, stream>>>(wq, wqkvb, 1048576);
  cvt_kernel<<<1024, 256, 0, stream>>>(wk, wqkvb + 4194304, 262144);
  cvt_kernel<<<1024, 256, 0, stream>>>(wv, wqkvb + 5242880, 262144);
  cvt_kernel<<<4096, 256, 0, stream>>>(wo, wob, 1048576);

  gemm_bt_kernel<true><<<dim3(64, 24), 256, 0, stream>>>(xb, wqkvb, xqkv, 8192, 3072, 2048);

  rope_kernel<5><<<32768, 256, 0, stream>>>(xqkv, fc, fs, qb, 0);
  rope_kernel<3><<<8192, 256, 0, stream>>>(xqkv, fc, fs, kb, 2048);
  convvt_kernel<<<16384, 256, 0, stream>>>(xqkv, vtb);

  attn_kernel<<<4096, 256, 0, stream>>>(qb, kb, vtb, attn);

  gemm_bt_kernel<false><<<dim3(64, 16), 256, 0, stream>>>(attn, wob, d_out, 8192, 2048, 2048);
}